// Round 11
// baseline (256.217 us; speedup 1.0000x reference)
//
#include <hip/hip_runtime.h>
#include <math.h>
#include <stdint.h>

#define B_ 32
#define N_ 1024
#define D_ 256
#define K_ 8
#define CAND 12

typedef unsigned short u16;
typedef unsigned int u32;
typedef __attribute__((ext_vector_type(8))) short s16x8;   // 8 bf16 (4 VGPRs)
typedef __attribute__((ext_vector_type(16))) float f32x16; // 32x32 accumulator

__device__ inline void cp16(const void* g, void* l) {
    // async global->LDS, 16B/lane; LDS dest = wave-uniform base + lane*16
    __builtin_amdgcn_global_load_lds((const __attribute__((address_space(1))) void*)g,
                                     (__attribute__((address_space(3))) void*)l, 16, 0, 0);
}

__device__ inline u16 f2bf(float f) {               // RNE float->bf16 bits
    uint32_t u = __float_as_uint(f);
    return (u16)((u + 0x7fffu + ((u >> 16) & 1u)) >> 16);
}
__device__ inline u32 umax32(u32 a, u32 b) { return a > b ? a : b; }
__device__ inline u32 umed3(u32 a, u32 b, u32 c) {  // median of 3, unsigned
    u32 d;
    asm("v_med3_u32 %0, %1, %2, %3" : "=v"(d) : "v"(a), "v"(b), "v"(c));
    return d;
}

// ------------- Kernel 1: fp64 inverse norms + normalized bf16 (hi only) -------------
__global__ __launch_bounds__(256) void prep_kernel(const float* __restrict__ tok,
                                                   double* __restrict__ invn,
                                                   u16* __restrict__ xhi) {
    const int tid = threadIdx.x;
    const int wave = tid >> 6, lane = tid & 63;
    const int row = blockIdx.x * 4 + wave;          // 32768 rows
    const float4 v = *reinterpret_cast<const float4*>(tok + (size_t)row * D_ + lane * 4);
    double s = (double)v.x * v.x + (double)v.y * v.y +
               (double)v.z * v.z + (double)v.w * v.w;
    #pragma unroll
    for (int off = 32; off > 0; off >>= 1) s += __shfl_xor(s, off, 64);
    const double inv = 1.0 / (sqrt(s) + 1e-8);
    if (lane == 0) invn[row] = inv;
    ushort4 h;
    h.x = f2bf((float)(v.x * inv));
    h.y = f2bf((float)(v.y * inv));
    h.z = f2bf((float)(v.z * inv));
    h.w = f2bf((float)(v.w * inv));
    *reinterpret_cast<ushort4*>(xhi + (size_t)row * D_ + lane * 4) = h;
}

// ------------- Kernel 2: MFMA sim, barrier-free wave-private pipeline -------------
// Frozen at R10 (wave-private 2x4KB dbuf, vmcnt(4), zero barriers, med3 scan insert).
__global__ __launch_bounds__(256, 4) void sim_topk_kernel(const u16* __restrict__ Xhi,
                                                          u32* __restrict__ candk,
                                                          int* __restrict__ candj) {
    __shared__ __align__(16) char smem[32768];       // 4 waves x 2 bufs x 4KB
    u32* keysL = (u32*)smem;                         // 12.3KB alias after main loop

    // XCD batch-affinity swizzle: id&7 = XCD; each XCD owns 4 whole batches.
    const int id    = blockIdx.x;             // 0..1023
    const int chunk = id >> 3;                // 0..127
    const int b   = (id & 7) * 4 + (chunk >> 5);
    const int rem = chunk & 31;
    const int i0  = (rem >> 1) * 64;
    const int jh  = rem & 1;                  // j-half: jt in [jh*8, jh*8+8)

    const int tid = threadIdx.x;
    const int w = tid >> 6, lane = tid & 63;
    const int mq = w >> 1, nq = w & 1;        // 2x2 wave grid of 32x32 tiles
    const int half = lane >> 5;
    const int il = lane & 31;

    const u16* XhiB = Xhi + (size_t)b * N_ * D_;

    const int srr = lane >> 3, spp = lane & 7;       // staging row-in-group, chunk-pos
    const int sgoff = (spp ^ srr) * 8;               // gathered source chunk (u16 units)
    char* const wbase = smem + w * 8192;             // private: 2 bufs x 4096B

    // per-lane LDS read offsets: local row il (32 rows x 128B), XOR-swizzled chunk
    const int x7 = il & 7;
    int loff[4];
    #pragma unroll
    for (int ks = 0; ks < 4; ++ks) loff[ks] = il * 128 + (((ks * 2 + half) ^ x7) * 16);

    auto STAGE_A = [&](int kc, int bufn) {           // 4 cp16 = 4KB: A rows mq*32..+31
        #pragma unroll
        for (int t = 0; t < 4; ++t)
            cp16(XhiB + (size_t)(i0 + mq * 32 + t * 8 + srr) * D_ + kc * 64 + sgoff,
                 wbase + bufn * 4096 + t * 1024);
    };
    auto STAGE_B = [&](int round, int bufn) {        // round = lt*4+kc; B rows nq*32..+31
        const int j0n = (jh * 8 + (round >> 2)) * 64;
        const int kcn = round & 3;
        #pragma unroll
        for (int t = 0; t < 4; ++t)
            cp16(XhiB + (size_t)(j0n + nq * 32 + t * 8 + srr) * D_ + kcn * 64 + sgoff,
                 wbase + bufn * 4096 + t * 1024);
    };

    // ---- barrier-free prologue: A hi fragments (4kc x 4ks) -> registers ----
    s16x8 Ahf[4][4];                                 // 64 regs, static-indexed only
    STAGE_A(0, 0);
    STAGE_A(1, 1);
    #pragma unroll
    for (int kc = 0; kc < 4; ++kc) {
        asm volatile("s_waitcnt vmcnt(4)" ::: "memory");   // own oldest 4 landed
        __builtin_amdgcn_sched_barrier(0);
        const char* ab = wbase + (kc & 1) * 4096;
        #pragma unroll
        for (int ks = 0; ks < 4; ++ks)
            Ahf[kc][ks] = *(const s16x8*)(ab + loff[ks]);
        asm volatile("s_waitcnt lgkmcnt(0)" ::: "memory"); // reads done before overwrite
        __builtin_amdgcn_sched_barrier(0);
        if (kc < 2) STAGE_A(kc + 2, kc & 1);
        else        STAGE_B(kc - 2, kc & 1);               // B rounds 0,1 in flight
    }

    const int diag_jt = i0 >> 6;                     // jt where j-tile == i-strip
    u32 keys[CAND];
    #pragma unroll
    for (int c = 0; c < CAND; ++c) keys[c] = 0u;     // real sims always pack > 0

    for (int lt = 0; lt < 8; ++lt) {                 // local jt
        const int jt = jh * 8 + lt;
        f32x16 acc;
        #pragma unroll
        for (int c = 0; c < 16; ++c) acc[c] = 0.0f;

        #pragma unroll
        for (int kc = 0; kc < 4; ++kc) {
            const int r = lt * 4 + kc;
            // wait for round r's 4 loads (round r+1's 4 stay in flight); no barriers
            if (r < 31) asm volatile("s_waitcnt vmcnt(4)" ::: "memory");
            else        asm volatile("s_waitcnt vmcnt(0)" ::: "memory");
            __builtin_amdgcn_sched_barrier(0);
            const char* bb = wbase + (r & 1) * 4096;
            s16x8 bh[4];
            #pragma unroll
            for (int ks = 0; ks < 4; ++ks)
                bh[ks] = *(const s16x8*)(bb + loff[ks]);
            asm volatile("s_waitcnt lgkmcnt(0)" ::: "memory"); // frags in regs
            __builtin_amdgcn_sched_barrier(0);
            if (r + 2 < 32) STAGE_B(r + 2, r & 1);   // refill the buffer just read
            #pragma unroll
            for (int ks = 0; ks < 4; ++ks)
                acc = __builtin_amdgcn_mfma_f32_32x32x16_bf16(bh[ks], Ahf[kc][ks], acc, 0, 0, 0);
        }

        // in-register scan: parallel med3 insert, 16 j-candidates of row i0+mq*32+il
        const u32 codebase = (u32)(jt << 4);         // jt<16, rg<16 -> 8-bit code
        const bool diag = (jt == diag_jt) && (mq == nq);
        #pragma unroll
        for (int rg = 0; rg < 16; ++rg) {
            const u32 u = __float_as_uint(acc[rg]);
            const u32 mono = u ^ ((u32)(((int)u) >> 31) | 0x80000000u); // order-preserving
            u32 key = (mono & 0xFFFFFF00u) | (codebase + (u32)rg);
            if (diag && ((rg & 3) + 8 * (rg >> 2) + 4 * half == il)) key = 0u; // kill self
            u32 prev = keys[0];
            keys[0] = umax32(keys[0], key);
            #pragma unroll
            for (int c = 1; c < CAND; ++c) {         // all levels independent (old values)
                const u32 cur = keys[c];
                keys[c] = umed3(key, cur, prev);
                prev = cur;
            }
        }
    }

    __syncthreads();                                 // drain + align; tiles dead -> keysL
    {
        const int r = mq * 32 + il;
        const int s = nq * 2 + half;
        u32* dst = keysL + (r * 4 + s) * CAND;
        #pragma unroll
        for (int c = 0; c < CAND; ++c) dst[c] = keys[c];
    }
    __syncthreads();

    // 4-way merge of sorted slot lists -> this half's top-12 per row -> global scratch
    if (tid < 64) {
        const u32* kl = keysL + tid * (4 * CAND);
        const size_t base = ((size_t)(b * N_ + i0 + tid) * 2 + jh) * CAND;
        int p0 = 0, p1 = 0, p2 = 0, p3 = 0;
        #pragma unroll
        for (int o = 0; o < CAND; ++o) {
            const u32 k0v = kl[p0];
            const u32 k1v = kl[CAND + p1];
            const u32 k2v = kl[2 * CAND + p2];
            const u32 k3v = kl[3 * CAND + p3];
            int bg = 0; u32 bv = k0v;
            if (k1v > bv) { bv = k1v; bg = 1; }
            if (k2v > bv) { bv = k2v; bg = 2; }
            if (k3v > bv) { bv = k3v; bg = 3; }
            const int code = (int)(bv & 0xFFu);
            const int jtv = code >> 4, rg = code & 15;
            // j = jt*64 + nq*32 + (rg&3)+8*(rg>>2)+4*half; slot bg: nq=bg>>1, half=bg&1
            candk[base + o] = bv;
            candj[base + o] = jtv * 64 + (bg >> 1) * 32 + (rg & 3) + 8 * (rg >> 2)
                              + 4 * (bg & 1);
            p0 += (bg == 0); p1 += (bg == 1); p2 += (bg == 2); p3 += (bg == 3);
        }
    }
}

// ------------- Kernel 2b: merge halves + fp64 rescore + exact top-8 -------------
// R11: fully-parallel rescore -- 8 rows/block, 384 threads, exactly ONE (row,cand)
// dot per quad (96 quads = 8x12), zero rounds: every 64-deep fp64 chain runs
// concurrently instead of 3 sequential rounds. Grid 4096 (4x TLP). qi re-reads hit
// L1 (12 quads share a row) -> LDS qi staging dropped. XCD batch-affinity swizzle
// re-derived for 128 chunks/batch (each XCD still owns 4 whole batches -- R5 lesson).
__global__ __launch_bounds__(384) void merge_rescore_kernel(const u32* __restrict__ candk,
                                                            const int* __restrict__ candj,
                                                            const float* __restrict__ tok,
                                                            const double* __restrict__ invn,
                                                            int* __restrict__ topk) {
    __shared__ int    mj[8 * CAND];
    __shared__ double dv[8 * CAND];
    const int tid = threadIdx.x;

    // XCD batch-affinity swizzle: id&7 = XCD; each XCD owns 4 whole batches.
    const int id    = blockIdx.x;                    // 0..4095
    const int chunk = id >> 3;                       // 0..511
    const int b     = (id & 7) * 4 + (chunk >> 7);
    const int i0    = (chunk & 127) * 8;
    const int R0    = b * N_ + i0;                   // global row base (8 rows)

    if (tid < 8) {                                   // 2-way merge of sorted halves
        const size_t base = (size_t)(R0 + tid) * 2 * CAND;
        int p0 = 0, p1 = 0;
        #pragma unroll
        for (int o = 0; o < CAND; ++o) {
            const u32 k0 = candk[base + p0];
            const u32 k1 = candk[base + CAND + p1];
            if (k0 >= k1) { mj[tid * CAND + o] = candj[base + p0];        ++p0; }
            else          { mj[tid * CAND + o] = candj[base + CAND + p1]; ++p1; }
        }
    }
    __syncthreads();

    // fp64 rescore: quad (4 lanes) per dot; one dot per quad, no loop
    {
        const int q = tid >> 2, ql = tid & 3;        // quad 0..95, lane-in-quad
        const int r = q / CAND, c = q % CAND;        // row 0..7, cand 0..11
        const int j = mj[r * CAND + c];
        const float* qi = tok + (size_t)(R0 + r) * D_;
        const float* qj = tok + (size_t)(b * N_ + j) * D_;
        double s = 0.0;
        #pragma unroll 4
        for (int k = 0; k < 16; ++k) {
            const float4 x = *reinterpret_cast<const float4*>(qi + k * 16 + ql * 4);
            const float4 y = *reinterpret_cast<const float4*>(qj + k * 16 + ql * 4);
            s += (double)x.x * y.x + (double)x.y * y.y +
                 (double)x.z * y.z + (double)x.w * y.w;
        }
        s += __shfl_xor(s, 1, 64);
        s += __shfl_xor(s, 2, 64);
        if (ql == 0) dv[r * CAND + c] = s * invn[R0 + r] * invn[b * N_ + j];
    }
    __syncthreads();

    // exact top-8 by fp64 rank (ties -> lower index, matching lax.top_k)
    if (tid < 8) {
        const int out_base = (R0 + tid) * K_;
        #pragma unroll 1
        for (int c = 0; c < CAND; ++c) {
            const double dc = dv[tid * CAND + c]; const int jc = mj[tid * CAND + c];
            int rank = 0;
            #pragma unroll 1
            for (int c2 = 0; c2 < CAND; ++c2) {
                if (c2 == c) continue;
                const double d2 = dv[tid * CAND + c2]; const int j2 = mj[tid * CAND + c2];
                if (d2 > dc || (d2 == dc && j2 < jc)) ++rank;
            }
            if (rank < K_) topk[out_base + rank] = jc;
        }
    }
}

// ------------- Kernel 3: fused mutual filter + FULL-ROW write (no memset) -------------
__global__ __launch_bounds__(256) void mutual_kernel(const int* __restrict__ topk,
                                                     float* __restrict__ out) {
    const int w = threadIdx.x >> 6, lane = threadIdx.x & 63;
    const int R = blockIdx.x * 4 + w;                // global row 0..32767
    const int i = R & (N_ - 1);
    const int bbase = R & ~(N_ - 1);                 // b * N

    int cu = 0; bool mu = false;
    if (lane < 8) {
        cu = topk[R * K_ + lane];                    // this row's candidate
        const int4* tj = reinterpret_cast<const int4*>(topk + (size_t)(bbase + cu) * K_);
        const int4 t0 = tj[0], t1 = tj[1];
        mu = (t0.x == i) | (t0.y == i) | (t0.z == i) | (t0.w == i) |
             (t1.x == i) | (t1.y == i) | (t1.z == i) | (t1.w == i);
    }
    const unsigned long long mm = __ballot(mu);      // bit u = candidate u mutual
    int c[8];
    #pragma unroll
    for (int u = 0; u < 8; ++u) c[u] = __shfl(cu, u, 64);

    float* orow = out + (size_t)R * N_;
    #pragma unroll
    for (int p = 0; p < 4; ++p) {                    // 4 x 1KB coalesced stores
        const int lo = p * 256 + lane * 4;
        float4 f = {0.f, 0.f, 0.f, 0.f};
        #pragma unroll
        for (int u = 0; u < 8; ++u) {
            const int rel = c[u] - lo;
            const float v = ((mm >> u) & 1ull) ? 1.0f : 0.0f;
            f.x = (rel == 0) ? v : f.x;
            f.y = (rel == 1) ? v : f.y;
            f.z = (rel == 2) ? v : f.z;
            f.w = (rel == 3) ? v : f.w;
        }
        *reinterpret_cast<float4*>(orow + lo) = f;
    }
}

extern "C" void kernel_launch(void* const* d_in, const int* in_sizes, int n_in,
                              void* d_out, int out_size, void* d_ws, size_t ws_size,
                              hipStream_t stream) {
    const float* tok = (const float*)d_in[0];
    float* out = (float*)d_out;
    double* invn = (double*)d_ws;                                  // 256 KB
    int* topk = (int*)((char*)d_ws + (size_t)B_ * N_ * sizeof(double)); // 1 MB
    // scratch lives in d_out (128 MB) until mutual_kernel overwrites every element:
    //   [0,16MB) xhi, [32,35MB) candk, [35,38MB) candj
    u16* xhi = (u16*)d_out;
    u32* candk = (u32*)((char*)d_out + (size_t)32 * 1024 * 1024);
    int* candj = (int*)((char*)d_out + (size_t)35 * 1024 * 1024);

    prep_kernel<<<dim3(B_ * N_ / 4), 256, 0, stream>>>(tok, invn, xhi);
    sim_topk_kernel<<<dim3(1024), 256, 0, stream>>>(xhi, candk, candj);
    merge_rescore_kernel<<<dim3(B_ * N_ / 8), 384, 0, stream>>>(candk, candj, tok, invn, topk);
    mutual_kernel<<<dim3(B_ * N_ / 4), 256, 0, stream>>>(topk, out);
}

// Round 12
// 242.061 us; speedup vs baseline: 1.0585x; 1.0585x over previous
//
#include <hip/hip_runtime.h>
#include <math.h>
#include <stdint.h>

#define B_ 32
#define N_ 1024
#define D_ 256
#define K_ 8
#define CAND 12

typedef unsigned short u16;
typedef unsigned int u32;
typedef __attribute__((ext_vector_type(8))) short s16x8;   // 8 bf16 (4 VGPRs)
typedef __attribute__((ext_vector_type(16))) float f32x16; // 32x32 accumulator

__device__ inline void cp16(const void* g, void* l) {
    // async global->LDS, 16B/lane; LDS dest = wave-uniform base + lane*16
    __builtin_amdgcn_global_load_lds((const __attribute__((address_space(1))) void*)g,
                                     (__attribute__((address_space(3))) void*)l, 16, 0, 0);
}

__device__ inline u16 f2bf(float f) {               // RNE float->bf16 bits
    uint32_t u = __float_as_uint(f);
    return (u16)((u + 0x7fffu + ((u >> 16) & 1u)) >> 16);
}
__device__ inline u32 umax32(u32 a, u32 b) { return a > b ? a : b; }
__device__ inline u32 umed3(u32 a, u32 b, u32 c) {  // median of 3, unsigned
    u32 d;
    asm("v_med3_u32 %0, %1, %2, %3" : "=v"(d) : "v"(a), "v"(b), "v"(c));
    return d;
}

// ------------- Kernel 1: fp64 inverse norms + normalized bf16 (hi only) -------------
__global__ __launch_bounds__(256) void prep_kernel(const float* __restrict__ tok,
                                                   double* __restrict__ invn,
                                                   u16* __restrict__ xhi) {
    const int tid = threadIdx.x;
    const int wave = tid >> 6, lane = tid & 63;
    const int row = blockIdx.x * 4 + wave;          // 32768 rows
    const float4 v = *reinterpret_cast<const float4*>(tok + (size_t)row * D_ + lane * 4);
    double s = (double)v.x * v.x + (double)v.y * v.y +
               (double)v.z * v.z + (double)v.w * v.w;
    #pragma unroll
    for (int off = 32; off > 0; off >>= 1) s += __shfl_xor(s, off, 64);
    const double inv = 1.0 / (sqrt(s) + 1e-8);
    if (lane == 0) invn[row] = inv;
    ushort4 h;
    h.x = f2bf((float)(v.x * inv));
    h.y = f2bf((float)(v.y * inv));
    h.z = f2bf((float)(v.z * inv));
    h.w = f2bf((float)(v.w * inv));
    *reinterpret_cast<ushort4*>(xhi + (size_t)row * D_ + lane * 4) = h;
}

// ------------- Kernel 2: MFMA sim, barrier-free wave-private pipeline -------------
// Frozen at R10 (wave-private 2x4KB dbuf, vmcnt(4), zero barriers, med3 scan insert).
__global__ __launch_bounds__(256, 4) void sim_topk_kernel(const u16* __restrict__ Xhi,
                                                          u32* __restrict__ candk,
                                                          int* __restrict__ candj) {
    __shared__ __align__(16) char smem[32768];       // 4 waves x 2 bufs x 4KB
    u32* keysL = (u32*)smem;                         // 12.3KB alias after main loop

    // XCD batch-affinity swizzle: id&7 = XCD; each XCD owns 4 whole batches.
    const int id    = blockIdx.x;             // 0..1023
    const int chunk = id >> 3;                // 0..127
    const int b   = (id & 7) * 4 + (chunk >> 5);
    const int rem = chunk & 31;
    const int i0  = (rem >> 1) * 64;
    const int jh  = rem & 1;                  // j-half: jt in [jh*8, jh*8+8)

    const int tid = threadIdx.x;
    const int w = tid >> 6, lane = tid & 63;
    const int mq = w >> 1, nq = w & 1;        // 2x2 wave grid of 32x32 tiles
    const int half = lane >> 5;
    const int il = lane & 31;

    const u16* XhiB = Xhi + (size_t)b * N_ * D_;

    const int srr = lane >> 3, spp = lane & 7;       // staging row-in-group, chunk-pos
    const int sgoff = (spp ^ srr) * 8;               // gathered source chunk (u16 units)
    char* const wbase = smem + w * 8192;             // private: 2 bufs x 4096B

    // per-lane LDS read offsets: local row il (32 rows x 128B), XOR-swizzled chunk
    const int x7 = il & 7;
    int loff[4];
    #pragma unroll
    for (int ks = 0; ks < 4; ++ks) loff[ks] = il * 128 + (((ks * 2 + half) ^ x7) * 16);

    auto STAGE_A = [&](int kc, int bufn) {           // 4 cp16 = 4KB: A rows mq*32..+31
        #pragma unroll
        for (int t = 0; t < 4; ++t)
            cp16(XhiB + (size_t)(i0 + mq * 32 + t * 8 + srr) * D_ + kc * 64 + sgoff,
                 wbase + bufn * 4096 + t * 1024);
    };
    auto STAGE_B = [&](int round, int bufn) {        // round = lt*4+kc; B rows nq*32..+31
        const int j0n = (jh * 8 + (round >> 2)) * 64;
        const int kcn = round & 3;
        #pragma unroll
        for (int t = 0; t < 4; ++t)
            cp16(XhiB + (size_t)(j0n + nq * 32 + t * 8 + srr) * D_ + kcn * 64 + sgoff,
                 wbase + bufn * 4096 + t * 1024);
    };

    // ---- barrier-free prologue: A hi fragments (4kc x 4ks) -> registers ----
    s16x8 Ahf[4][4];                                 // 64 regs, static-indexed only
    STAGE_A(0, 0);
    STAGE_A(1, 1);
    #pragma unroll
    for (int kc = 0; kc < 4; ++kc) {
        asm volatile("s_waitcnt vmcnt(4)" ::: "memory");   // own oldest 4 landed
        __builtin_amdgcn_sched_barrier(0);
        const char* ab = wbase + (kc & 1) * 4096;
        #pragma unroll
        for (int ks = 0; ks < 4; ++ks)
            Ahf[kc][ks] = *(const s16x8*)(ab + loff[ks]);
        asm volatile("s_waitcnt lgkmcnt(0)" ::: "memory"); // reads done before overwrite
        __builtin_amdgcn_sched_barrier(0);
        if (kc < 2) STAGE_A(kc + 2, kc & 1);
        else        STAGE_B(kc - 2, kc & 1);               // B rounds 0,1 in flight
    }

    const int diag_jt = i0 >> 6;                     // jt where j-tile == i-strip
    u32 keys[CAND];
    #pragma unroll
    for (int c = 0; c < CAND; ++c) keys[c] = 0u;     // real sims always pack > 0

    for (int lt = 0; lt < 8; ++lt) {                 // local jt
        const int jt = jh * 8 + lt;
        f32x16 acc;
        #pragma unroll
        for (int c = 0; c < 16; ++c) acc[c] = 0.0f;

        #pragma unroll
        for (int kc = 0; kc < 4; ++kc) {
            const int r = lt * 4 + kc;
            // wait for round r's 4 loads (round r+1's 4 stay in flight); no barriers
            if (r < 31) asm volatile("s_waitcnt vmcnt(4)" ::: "memory");
            else        asm volatile("s_waitcnt vmcnt(0)" ::: "memory");
            __builtin_amdgcn_sched_barrier(0);
            const char* bb = wbase + (r & 1) * 4096;
            s16x8 bh[4];
            #pragma unroll
            for (int ks = 0; ks < 4; ++ks)
                bh[ks] = *(const s16x8*)(bb + loff[ks]);
            asm volatile("s_waitcnt lgkmcnt(0)" ::: "memory"); // frags in regs
            __builtin_amdgcn_sched_barrier(0);
            if (r + 2 < 32) STAGE_B(r + 2, r & 1);   // refill the buffer just read
            #pragma unroll
            for (int ks = 0; ks < 4; ++ks)
                acc = __builtin_amdgcn_mfma_f32_32x32x16_bf16(bh[ks], Ahf[kc][ks], acc, 0, 0, 0);
        }

        // in-register scan: parallel med3 insert, 16 j-candidates of row i0+mq*32+il
        const u32 codebase = (u32)(jt << 4);         // jt<16, rg<16 -> 8-bit code
        const bool diag = (jt == diag_jt) && (mq == nq);
        #pragma unroll
        for (int rg = 0; rg < 16; ++rg) {
            const u32 u = __float_as_uint(acc[rg]);
            const u32 mono = u ^ ((u32)(((int)u) >> 31) | 0x80000000u); // order-preserving
            u32 key = (mono & 0xFFFFFF00u) | (codebase + (u32)rg);
            if (diag && ((rg & 3) + 8 * (rg >> 2) + 4 * half == il)) key = 0u; // kill self
            u32 prev = keys[0];
            keys[0] = umax32(keys[0], key);
            #pragma unroll
            for (int c = 1; c < CAND; ++c) {         // all levels independent (old values)
                const u32 cur = keys[c];
                keys[c] = umed3(key, cur, prev);
                prev = cur;
            }
        }
    }

    __syncthreads();                                 // drain + align; tiles dead -> keysL
    {
        const int r = mq * 32 + il;
        const int s = nq * 2 + half;
        u32* dst = keysL + (r * 4 + s) * CAND;
        #pragma unroll
        for (int c = 0; c < CAND; ++c) dst[c] = keys[c];
    }
    __syncthreads();

    // 4-way merge of sorted slot lists -> this half's top-12 per row -> global scratch
    if (tid < 64) {
        const u32* kl = keysL + tid * (4 * CAND);
        const size_t base = ((size_t)(b * N_ + i0 + tid) * 2 + jh) * CAND;
        int p0 = 0, p1 = 0, p2 = 0, p3 = 0;
        #pragma unroll
        for (int o = 0; o < CAND; ++o) {
            const u32 k0v = kl[p0];
            const u32 k1v = kl[CAND + p1];
            const u32 k2v = kl[2 * CAND + p2];
            const u32 k3v = kl[3 * CAND + p3];
            int bg = 0; u32 bv = k0v;
            if (k1v > bv) { bv = k1v; bg = 1; }
            if (k2v > bv) { bv = k2v; bg = 2; }
            if (k3v > bv) { bv = k3v; bg = 3; }
            const int code = (int)(bv & 0xFFu);
            const int jtv = code >> 4, rg = code & 15;
            // j = jt*64 + nq*32 + (rg&3)+8*(rg>>2)+4*half; slot bg: nq=bg>>1, half=bg&1
            candk[base + o] = bv;
            candj[base + o] = jtv * 64 + (bg >> 1) * 32 + (rg & 3) + 8 * (rg >> 2)
                              + 4 * (bg & 1);
            p0 += (bg == 0); p1 += (bg == 1); p2 += (bg == 2); p3 += (bg == 3);
        }
    }
}

// ------------- Kernel 2b: merge halves + fp64 rescore + exact top-8 -------------
// R12: reverted to the R10 configuration (best measured: 243.2us total). 32 rows/block,
// 512 threads, LDS-staged qi (260-stride), 3-round quad rescore. R11's 8-row/384-thread
// "fully parallel" variant regressed +13us (tiny blocks: dispatch overhead + 2% thread
// utilization in merge/rank phases + lost qj L2 locality).
__global__ __launch_bounds__(512, 4) void merge_rescore_kernel(const u32* __restrict__ candk,
                                                               const int* __restrict__ candj,
                                                               const float* __restrict__ tok,
                                                               const double* __restrict__ invn,
                                                               int* __restrict__ topk) {
    __shared__ float  qiL[32 * 260];                 // 260-stride: +4-float row pad
    __shared__ int    mj[32 * CAND];
    __shared__ double dv[32 * CAND];
    const int tid = threadIdx.x;

    // XCD batch-affinity swizzle: id&7 = XCD; each XCD owns 4 whole batches.
    const int id    = blockIdx.x;                    // 0..1023
    const int chunk = id >> 3;                       // 0..127
    const int b     = (id & 7) * 4 + (chunk >> 5);
    const int i0    = (chunk & 31) * 32;
    const int R0    = b * N_ + i0;                   // global row base (32 rows)

    // cooperative stage: 32 contiguous rows = 8192 floats, fully coalesced
    {
        const float4* src = reinterpret_cast<const float4*>(tok + (size_t)R0 * D_);
        #pragma unroll
        for (int p = 0; p < 4; ++p) {
            const int v4 = p * 512 + tid;            // float4 index 0..2047
            const int r = v4 >> 6, cc = v4 & 63;     // row, float4-in-row
            *reinterpret_cast<float4*>(&qiL[r * 260 + cc * 4]) = src[v4];
        }
    }
    if (tid < 32) {                                  // 2-way merge of sorted halves
        const size_t base = (size_t)(R0 + tid) * 2 * CAND;
        int p0 = 0, p1 = 0;
        #pragma unroll
        for (int o = 0; o < CAND; ++o) {
            const u32 k0 = candk[base + p0];
            const u32 k1 = candk[base + CAND + p1];
            if (k0 >= k1) { mj[tid * CAND + o] = candj[base + p0];        ++p0; }
            else          { mj[tid * CAND + o] = candj[base + CAND + p1]; ++p1; }
        }
    }
    __syncthreads();

    // fp64 rescore: quad (4 lanes) per dot; qi from LDS, qj gathered from L2
    {
        const int q = tid >> 2, ql = tid & 3;        // quad 0..127, lane-in-quad
        const int r = q >> 2;                        // row 0..31
        const float* qiR = &qiL[r * 260];
        const double di = invn[R0 + r];
        #pragma unroll 1
        for (int rr = 0; rr < 3; ++rr) {
            const int c = (q & 3) * 3 + rr;          // cand 0..11
            const int j = mj[r * CAND + c];
            const float* qj = tok + (size_t)(b * N_ + j) * D_;
            double s = 0.0;
            #pragma unroll 4
            for (int k = 0; k < 16; ++k) {
                const float4 x = *reinterpret_cast<const float4*>(qiR + k * 16 + ql * 4);
                const float4 y = *reinterpret_cast<const float4*>(qj + k * 16 + ql * 4);
                s += (double)x.x * y.x + (double)x.y * y.y +
                     (double)x.z * y.z + (double)x.w * y.w;
            }
            s += __shfl_xor(s, 1, 64);
            s += __shfl_xor(s, 2, 64);
            if (ql == 0) dv[r * CAND + c] = s * di * invn[b * N_ + j];
        }
    }
    __syncthreads();

    // exact top-8 by fp64 rank (ties -> lower index, matching lax.top_k)
    if (tid < 32) {
        const int out_base = (R0 + tid) * K_;
        #pragma unroll 1
        for (int c = 0; c < CAND; ++c) {
            const double dc = dv[tid * CAND + c]; const int jc = mj[tid * CAND + c];
            int rank = 0;
            #pragma unroll 1
            for (int c2 = 0; c2 < CAND; ++c2) {
                if (c2 == c) continue;
                const double d2 = dv[tid * CAND + c2]; const int j2 = mj[tid * CAND + c2];
                if (d2 > dc || (d2 == dc && j2 < jc)) ++rank;
            }
            if (rank < K_) topk[out_base + rank] = jc;
        }
    }
}

// ------------- Kernel 3: fused mutual filter + FULL-ROW write (no memset) -------------
__global__ __launch_bounds__(256) void mutual_kernel(const int* __restrict__ topk,
                                                     float* __restrict__ out) {
    const int w = threadIdx.x >> 6, lane = threadIdx.x & 63;
    const int R = blockIdx.x * 4 + w;                // global row 0..32767
    const int i = R & (N_ - 1);
    const int bbase = R & ~(N_ - 1);                 // b * N

    int cu = 0; bool mu = false;
    if (lane < 8) {
        cu = topk[R * K_ + lane];                    // this row's candidate
        const int4* tj = reinterpret_cast<const int4*>(topk + (size_t)(bbase + cu) * K_);
        const int4 t0 = tj[0], t1 = tj[1];
        mu = (t0.x == i) | (t0.y == i) | (t0.z == i) | (t0.w == i) |
             (t1.x == i) | (t1.y == i) | (t1.z == i) | (t1.w == i);
    }
    const unsigned long long mm = __ballot(mu);      // bit u = candidate u mutual
    int c[8];
    #pragma unroll
    for (int u = 0; u < 8; ++u) c[u] = __shfl(cu, u, 64);

    float* orow = out + (size_t)R * N_;
    #pragma unroll
    for (int p = 0; p < 4; ++p) {                    // 4 x 1KB coalesced stores
        const int lo = p * 256 + lane * 4;
        float4 f = {0.f, 0.f, 0.f, 0.f};
        #pragma unroll
        for (int u = 0; u < 8; ++u) {
            const int rel = c[u] - lo;
            const float v = ((mm >> u) & 1ull) ? 1.0f : 0.0f;
            f.x = (rel == 0) ? v : f.x;
            f.y = (rel == 1) ? v : f.y;
            f.z = (rel == 2) ? v : f.z;
            f.w = (rel == 3) ? v : f.w;
        }
        *reinterpret_cast<float4*>(orow + lo) = f;
    }
}

extern "C" void kernel_launch(void* const* d_in, const int* in_sizes, int n_in,
                              void* d_out, int out_size, void* d_ws, size_t ws_size,
                              hipStream_t stream) {
    const float* tok = (const float*)d_in[0];
    float* out = (float*)d_out;
    double* invn = (double*)d_ws;                                  // 256 KB
    int* topk = (int*)((char*)d_ws + (size_t)B_ * N_ * sizeof(double)); // 1 MB
    // scratch lives in d_out (128 MB) until mutual_kernel overwrites every element:
    //   [0,16MB) xhi, [32,35MB) candk, [35,38MB) candj
    u16* xhi = (u16*)d_out;
    u32* candk = (u32*)((char*)d_out + (size_t)32 * 1024 * 1024);
    int* candj = (int*)((char*)d_out + (size_t)35 * 1024 * 1024);

    prep_kernel<<<dim3(B_ * N_ / 4), 256, 0, stream>>>(tok, invn, xhi);
    sim_topk_kernel<<<dim3(1024), 256, 0, stream>>>(xhi, candk, candj);
    merge_rescore_kernel<<<dim3(B_ * N_ / 32), 512, 0, stream>>>(candk, candj, tok, invn, topk);
    mutual_kernel<<<dim3(B_ * N_ / 4), 256, 0, stream>>>(topk, out);
}